// Round 8
// baseline (378.760 us; speedup 1.0000x reference)
//
#include <hip/hip_runtime.h>
#include <hip/hip_bf16.h>

// GCN 7-layer forward on MI355X. R8:
//  - fused agg+GEMV for 64-input agg-first layers (L2,L5,L6): one node per
//    wave (keeps gather parallelism - R6 lesson), GEMV via reg-resident fp16
//    W columns + shfl t-broadcast. No LDS, no barrier. t stays fp32.
//  - L7 GEMV folded into L6 epilogue (g6 never materialized).
//  - hist_reduce absorbs scan_blk. Dispatches 22 -> 17.

#define IN_F 128
#define NSLICE 60
#define SHB 13          // 8192 nodes/shard, 32 KB LDS
#define NSHARD 5        // ceil(40000/8192)

typedef __attribute__((ext_vector_type(8))) short short8v;   // 8 bf16
typedef __attribute__((ext_vector_type(4))) float f32x4;
typedef __attribute__((ext_vector_type(8))) _Float16 half8v; // 16 B

static __device__ __forceinline__ unsigned short f2bf(float x) {
    unsigned u = __builtin_bit_cast(unsigned, x);
    unsigned r = (u + 0x7FFFu + ((u >> 16) & 1u)) >> 16;   // rn-even
    return (unsigned short)r;
}
static __device__ __forceinline__ float bf2f(unsigned short h) {
    unsigned u = ((unsigned)h) << 16;
    return __builtin_bit_cast(float, u);
}

// ---------------- LDS histogram: grid (NSLICE, NSHARD, 2) ----------------

__global__ __launch_bounds__(256) void hist2_kernel(const int* __restrict__ src,
                                                    const int* __restrict__ dst,
                                                    int* __restrict__ scratch, int E) {
    constexpr int SH = 1 << SHB;
    __shared__ int h[SH];
    const int t = threadIdx.x;
    const int b = blockIdx.x;            // edge slice
    const int s = blockIdx.y;            // node shard
    const int z = blockIdx.z;            // 0 = src (out-deg), 1 = dst (in-deg)
    const int* idx = z ? dst : src;
    for (int i = t; i < SH; i += 256) h[i] = 0;
    __syncthreads();
    const int per = (E + NSLICE - 1) / NSLICE;
    const int lo = b * per;
    const int hiE = min(lo + per, E);
    const int base = s << SHB;
    for (int e = lo + t; e < hiE; e += 256) {
        unsigned a = (unsigned)(idx[e] - base);
        if (a < (unsigned)SH) atomicAdd(&h[a], 1);
    }
    __syncthreads();
    int* so = scratch + ((size_t)((z * NSHARD + s) * NSLICE + b) << SHB);
    for (int i = t; i < SH; i += 256) so[i] = h[i];
}

// merged: per-node degree sums + norms + per-1024-node block sums (ex scan_blk)
// grid = 40 blocks (40960 padded nodes), 4 nodes/thread
__global__ __launch_bounds__(256) void hist_reduce_blk(
    const int* __restrict__ scratch, int* __restrict__ in_deg,
    float* __restrict__ out_nrm, float* __restrict__ in_nrm,
    int* __restrict__ blockSums) {
    constexpr int SH = 1 << SHB;
    __shared__ int ws4[4];
    const int t = threadIdx.x;
    const int base = blockIdx.x * 1024 + t * 4;
    const int s = base >> SHB;
    const int i = base & (SH - 1);
    int od[4] = {0, 0, 0, 0}, id[4] = {0, 0, 0, 0};
    const int* po = scratch + (((size_t)s * NSLICE) << SHB) + i;
    const int* pi = scratch + (((size_t)(NSHARD + s) * NSLICE) << SHB) + i;
    for (int b = 0; b < NSLICE; ++b) {
        int4 o4 = *reinterpret_cast<const int4*>(po + ((size_t)b << SHB));
        int4 i4 = *reinterpret_cast<const int4*>(pi + ((size_t)b << SHB));
        od[0] += o4.x; od[1] += o4.y; od[2] += o4.z; od[3] += o4.w;
        id[0] += i4.x; id[1] += i4.y; id[2] += i4.z; id[3] += i4.w;
    }
    *reinterpret_cast<int4*>(&in_deg[base]) = make_int4(id[0], id[1], id[2], id[3]);
    float4 onf, inf;
    onf.x = od[0] > 0 ? rsqrtf((float)od[0]) : 0.f;
    onf.y = od[1] > 0 ? rsqrtf((float)od[1]) : 0.f;
    onf.z = od[2] > 0 ? rsqrtf((float)od[2]) : 0.f;
    onf.w = od[3] > 0 ? rsqrtf((float)od[3]) : 0.f;
    inf.x = id[0] > 0 ? rsqrtf((float)id[0]) : 0.f;
    inf.y = id[1] > 0 ? rsqrtf((float)id[1]) : 0.f;
    inf.z = id[2] > 0 ? rsqrtf((float)id[2]) : 0.f;
    inf.w = id[3] > 0 ? rsqrtf((float)id[3]) : 0.f;
    *reinterpret_cast<float4*>(&out_nrm[base]) = onf;
    *reinterpret_cast<float4*>(&in_nrm[base]) = inf;
    int ssum = id[0] + id[1] + id[2] + id[3];
#pragma unroll
    for (int off = 32; off > 0; off >>= 1) ssum += __shfl_down(ssum, off);
    if ((t & 63) == 0) ws4[t >> 6] = ssum;
    __syncthreads();
    if (t == 0) blockSums[blockIdx.x] = ws4[0] + ws4[1] + ws4[2] + ws4[3];
}

__global__ __launch_bounds__(64) void scan_top_kernel(const int* __restrict__ blockSums,
                                                      int* __restrict__ blockOffs,
                                                      int* __restrict__ row_off, int NB, int N) {
    const int t = threadIdx.x;
    int orig = (t < NB) ? blockSums[t] : 0;
    int v = orig;
#pragma unroll
    for (int off = 1; off < 64; off <<= 1) {
        int u = __shfl_up(v, off);
        if (t >= off) v += u;
    }
    if (t < NB) blockOffs[t] = v - orig;
    if (t == 63) row_off[N] = v;
}

__global__ __launch_bounds__(256) void scan_fill_kernel(const int* __restrict__ deg,
                                                        const int* __restrict__ blockOffs,
                                                        int* __restrict__ row_off, int N) {
    __shared__ int wtot[4];
    const int t = threadIdx.x;
    const int lane = t & 63;
    const int wid = t >> 6;
    const int base = blockIdx.x * 1024 + t * 4;
    int4 v = make_int4(0, 0, 0, 0);
    if (base + 3 < N) v = *reinterpret_cast<const int4*>(&deg[base]);
    else if (base < N) {
        v.x = deg[base];
        if (base + 1 < N) v.y = deg[base + 1];
        if (base + 2 < N) v.z = deg[base + 2];
    }
    const int s = v.x + v.y + v.z + v.w;
    int incl = s;
#pragma unroll
    for (int off = 1; off < 64; off <<= 1) {
        int u = __shfl_up(incl, off);
        if (lane >= off) incl += u;
    }
    if (lane == 63) wtot[wid] = incl;
    __syncthreads();
    int pre = blockOffs[blockIdx.x] + incl - s;
    for (int i = 0; i < wid; ++i) pre += wtot[i];
    if (base < N) {
        int run = pre;
        row_off[base] = run; run += v.x;
        if (base + 1 < N) { row_off[base + 1] = run; run += v.y; }
        if (base + 2 < N) { row_off[base + 2] = run; run += v.z; }
        if (base + 3 < N) { row_off[base + 3] = run; }
    }
}

// per-(slice,node) dst counts -> global base positions
__global__ void slice_base_kernel(int* __restrict__ scratch,
                                  const int* __restrict__ row_off, int N) {
    constexpr int SH = 1 << SHB;
    int n = blockIdx.x * blockDim.x + threadIdx.x;
    if (n >= N) return;
    int s = n >> SHB;
    int i = n & (SH - 1);
    int run = row_off[n];
    for (int b = 0; b < NSLICE; ++b) {
        size_t off = ((size_t)((NSHARD + s) * NSLICE + b) << SHB) + i;
        int c = scratch[off];
        scratch[off] = run;
        run += c;
    }
}

// place edges using LDS cursors seeded from slice bases; no global atomics
__global__ __launch_bounds__(256) void fill2_kernel(const int* __restrict__ src,
                                                    const int* __restrict__ dst,
                                                    const int* __restrict__ scratch,
                                                    int* __restrict__ csr, int E) {
    constexpr int SH = 1 << SHB;
    __shared__ int cur[SH];
    const int t = threadIdx.x;
    const int b = blockIdx.x;   // slice
    const int s = blockIdx.y;   // shard
    const int* base = scratch + ((size_t)((NSHARD + s) * NSLICE + b) << SHB);
    for (int i = t; i < SH; i += 256) cur[i] = base[i];
    __syncthreads();
    const int per = (E + NSLICE - 1) / NSLICE;
    const int lo = b * per;
    const int hiE = min(lo + per, E);
    const int nb = s << SHB;
    for (int e = lo + t; e < hiE; e += 256) {
        unsigned a = (unsigned)(dst[e] - nb);
        if (a < (unsigned)SH) {
            int pos = atomicAdd(&cur[a], 1);
            csr[pos] = src[e];
        }
    }
}

// ---------------- weight split/transpose (+ optional fp16 transpose) ----------------

struct WDesc { const float* w; unsigned short* th; unsigned short* tl; _Float16* t16; int K; int N; };
struct WPack { WDesc d[6]; };

__global__ __launch_bounds__(256) void split_w_kernel(WPack p) {
    WDesc d = p.d[blockIdx.x];
    int i = blockIdx.y * 256 + threadIdx.x;
    if (i >= d.K * d.N) return;
    int k = i / d.N, n = i - k * d.N;
    float v = d.w[i];
    unsigned short h = f2bf(v);
    d.th[(size_t)n * d.K + k] = h;
    d.tl[(size_t)n * d.K + k] = f2bf(v - bf2f(h));
    if (d.t16) d.t16[(size_t)n * d.K + k] = (_Float16)v;
}

// ---------------- L1 GEMM: fp32 input, scale+split in registers ----------------

template<int K, int NOUT>
__global__ __launch_bounds__(256) void gemm_mfma_f32(
    const float* __restrict__ X,
    const unsigned short* __restrict__ Bh, const unsigned short* __restrict__ Bl,
    const float* __restrict__ pre, _Float16* __restrict__ Y16, int M) {
    constexpr int NT = NOUT / 16;
    const int lane = threadIdx.x & 63;
    const int wv = threadIdx.x >> 6;
    const int r0 = blockIdx.x * 64 + wv * 16;
    const int arow = r0 + (lane & 15);
    const int kg = (lane >> 4) * 8;
    const float sc = pre[arow];

    f32x4 acc[NT];
#pragma unroll
    for (int n = 0; n < NT; ++n) acc[n] = (f32x4){0.f, 0.f, 0.f, 0.f};

    for (int kk = 0; kk < K; kk += 32) {
        const float* ap = &X[(size_t)arow * K + kk + kg];
        float4 v0 = *reinterpret_cast<const float4*>(ap);
        float4 v1 = *reinterpret_cast<const float4*>(ap + 4);
        float a[8] = {v0.x, v0.y, v0.z, v0.w, v1.x, v1.y, v1.z, v1.w};
        short8v a_h, a_l;
#pragma unroll
        for (int j = 0; j < 8; ++j) {
            float f = a[j] * sc;
            unsigned short hh = f2bf(f);
            a_h[j] = (short)hh;
            a_l[j] = (short)f2bf(f - bf2f(hh));
        }
#pragma unroll
        for (int n = 0; n < NT; ++n) {
            int col = n * 16 + (lane & 15);
            short8v b_h = *reinterpret_cast<const short8v*>(Bh + (size_t)col * K + kk + kg);
            short8v b_l = *reinterpret_cast<const short8v*>(Bl + (size_t)col * K + kk + kg);
            acc[n] = __builtin_amdgcn_mfma_f32_16x16x32_bf16(a_h, b_h, acc[n], 0, 0, 0);
            acc[n] = __builtin_amdgcn_mfma_f32_16x16x32_bf16(a_h, b_l, acc[n], 0, 0, 0);
            acc[n] = __builtin_amdgcn_mfma_f32_16x16x32_bf16(a_l, b_h, acc[n], 0, 0, 0);
        }
    }
    const int c0 = lane & 15;
    const int rr = r0 + (lane >> 4) * 4;
#pragma unroll
    for (int n = 0; n < NT; ++n) {
        const int col = n * 16 + c0;
#pragma unroll
        for (int j = 0; j < 4; ++j)
            Y16[(size_t)(rr + j) * NOUT + col] = (_Float16)acc[n][j];
    }
}

// ---------------- GEMM: fp16 A, split to bf16 hi/lo in registers ----------------

template<int K, int NOUT, bool EPI>
__global__ __launch_bounds__(256) void gemm_h16(
    const _Float16* __restrict__ X,
    const unsigned short* __restrict__ Bh, const unsigned short* __restrict__ Bl,
    const float* __restrict__ r_nrm, const float* __restrict__ s_nrm,
    const float* __restrict__ bias, _Float16* __restrict__ Y16, int M) {
    constexpr int NT = NOUT / 16;
    const int lane = threadIdx.x & 63;
    const int wv = threadIdx.x >> 6;
    const int r0 = blockIdx.x * 64 + wv * 16;
    const int arow = r0 + (lane & 15);
    const int kg = (lane >> 4) * 8;

    f32x4 acc[NT];
#pragma unroll
    for (int n = 0; n < NT; ++n) acc[n] = (f32x4){0.f, 0.f, 0.f, 0.f};

    for (int kk = 0; kk < K; kk += 32) {
        half8v av = *reinterpret_cast<const half8v*>(&X[(size_t)arow * K + kk + kg]);
        short8v a_h, a_l;
#pragma unroll
        for (int j = 0; j < 8; ++j) {
            float f = (float)av[j];
            unsigned short hh = f2bf(f);
            a_h[j] = (short)hh;
            a_l[j] = (short)f2bf(f - bf2f(hh));
        }
#pragma unroll
        for (int n = 0; n < NT; ++n) {
            int col = n * 16 + (lane & 15);
            short8v b_h = *reinterpret_cast<const short8v*>(Bh + (size_t)col * K + kk + kg);
            short8v b_l = *reinterpret_cast<const short8v*>(Bl + (size_t)col * K + kk + kg);
            acc[n] = __builtin_amdgcn_mfma_f32_16x16x32_bf16(a_h, b_h, acc[n], 0, 0, 0);
            acc[n] = __builtin_amdgcn_mfma_f32_16x16x32_bf16(a_h, b_l, acc[n], 0, 0, 0);
            acc[n] = __builtin_amdgcn_mfma_f32_16x16x32_bf16(a_l, b_h, acc[n], 0, 0, 0);
        }
    }
    const int c0 = lane & 15;
    const int rr = r0 + (lane >> 4) * 4;
#pragma unroll
    for (int n = 0; n < NT; ++n) {
        const int col = n * 16 + c0;
        const float bcol = EPI ? bias[col] : 0.f;
#pragma unroll
        for (int j = 0; j < 4; ++j) {
            const int row = rr + j;
            float y = acc[n][j];
            if (EPI) {
                y = fmaf(y, r_nrm[row], bcol);
                y = fmaxf(y, 0.f);
                y *= s_nrm[row];
            }
            Y16[(size_t)row * NOUT + col] = (_Float16)y;
        }
    }
}

// ---------------- standalone fp16 CSR aggregation (L1, L3, L4) ----------------

template<int F, bool EPI>
__global__ __launch_bounds__(256) void agg_h16(
    const _Float16* __restrict__ X, const int* __restrict__ csr,
    const int* __restrict__ row_off, const float* __restrict__ r_nrm,
    const float* __restrict__ s_nrm, const float* __restrict__ bias,
    _Float16* __restrict__ Y16, int N) {
    constexpr int LPE = F / 8;
    constexpr int EPW = 64 / LPE;
    const int lane = threadIdx.x & 63;
    const int node = blockIdx.x * (blockDim.x >> 6) + (threadIdx.x >> 6);
    if (node >= N) return;
    const int g = lane / LPE;
    const int c = lane % LPE;
    const int lo = row_off[node];
    const int hi = row_off[node + 1];
    float acc[8], acc2[8];
#pragma unroll
    for (int j = 0; j < 8; ++j) { acc[j] = 0.f; acc2[j] = 0.f; }
    int e = lo + g;
    for (; e + EPW < hi; e += 2 * EPW) {
        int s0 = csr[e];
        int s1 = csr[e + EPW];
        half8v x0 = *reinterpret_cast<const half8v*>(&X[(size_t)s0 * F + c * 8]);
        half8v x1 = *reinterpret_cast<const half8v*>(&X[(size_t)s1 * F + c * 8]);
#pragma unroll
        for (int j = 0; j < 8; ++j) { acc[j] += (float)x0[j]; acc2[j] += (float)x1[j]; }
    }
    if (e < hi) {
        int s0 = csr[e];
        half8v x0 = *reinterpret_cast<const half8v*>(&X[(size_t)s0 * F + c * 8]);
#pragma unroll
        for (int j = 0; j < 8; ++j) acc[j] += (float)x0[j];
    }
#pragma unroll
    for (int j = 0; j < 8; ++j) acc[j] += acc2[j];
#pragma unroll
    for (int m = LPE; m < 64; m <<= 1) {
#pragma unroll
        for (int j = 0; j < 8; ++j) acc[j] += __shfl_xor(acc[j], m);
    }
    if (lane < LPE) {
        half8v o;
        if (EPI) {
            float rn = r_nrm[node];
            float sn = s_nrm[node];
#pragma unroll
            for (int j = 0; j < 8; ++j) {
                float y = fmaf(acc[j], rn, bias[lane * 8 + j]);
                o[j] = (_Float16)(fmaxf(y, 0.f) * sn);
            }
        } else {
#pragma unroll
            for (int j = 0; j < 8; ++j) o[j] = (_Float16)acc[j];
        }
        *reinterpret_cast<half8v*>(&Y16[(size_t)node * F + lane * 8]) = o;
    }
}

// ---------------- fused agg+GEMV (64-input agg-first layers L2,L5,L6) ----------------
// One node per wave (gather parallelism preserved). After the xor-reduce ALL
// lanes hold the full fp32 t-chunk (features (lane&7)*8..+7). GEMV: 64 shfl
// broadcasts x reg-resident fp16 W columns. Epilogue relu(o*r+b)*s.
// LAST: dot with W7 + wave-reduce -> T7 (g6 never materialized).

template<int NOUT, bool LAST>
__global__ __launch_bounds__(256) void fused_agv(
    const _Float16* __restrict__ X, const int* __restrict__ csr,
    const int* __restrict__ row_off, const _Float16* __restrict__ Wt,
    const float* __restrict__ r_nrm, const float* __restrict__ s_nrm,
    const float* __restrict__ bias, const float* __restrict__ W7,
    _Float16* __restrict__ Y16, float* __restrict__ T7, int N) {
    const int lane = threadIdx.x & 63;
    const int node = blockIdx.x * 4 + (threadIdx.x >> 6);
    if (node >= N) return;
    const int g = lane >> 3;   // edge group (8 in flight)
    const int c = lane & 7;    // feature chunk
    const int lo = row_off[node];
    const int hi = row_off[node + 1];
    float acc[8], acc2[8];
#pragma unroll
    for (int j = 0; j < 8; ++j) { acc[j] = 0.f; acc2[j] = 0.f; }
    int e = lo + g;
    for (; e + 8 < hi; e += 16) {
        int s0 = csr[e];
        int s1 = csr[e + 8];
        half8v x0 = *reinterpret_cast<const half8v*>(&X[(size_t)s0 * 64 + c * 8]);
        half8v x1 = *reinterpret_cast<const half8v*>(&X[(size_t)s1 * 64 + c * 8]);
#pragma unroll
        for (int j = 0; j < 8; ++j) { acc[j] += (float)x0[j]; acc2[j] += (float)x1[j]; }
    }
    if (e < hi) {
        int s0 = csr[e];
        half8v x0 = *reinterpret_cast<const half8v*>(&X[(size_t)s0 * 64 + c * 8]);
#pragma unroll
        for (int j = 0; j < 8; ++j) acc[j] += (float)x0[j];
    }
#pragma unroll
    for (int j = 0; j < 8; ++j) acc[j] += acc2[j];
#pragma unroll
    for (int m = 8; m < 64; m <<= 1) {
#pragma unroll
        for (int j = 0; j < 8; ++j) acc[j] += __shfl_xor(acc[j], m);
    }
    // every lane: acc[j] = t[c*8+j] (fp32, full sum)

    // W columns for this lane's output(s), fp16 in registers
    half8v w0[8];
#pragma unroll
    for (int q = 0; q < 8; ++q)
        w0[q] = *reinterpret_cast<const half8v*>(&Wt[(size_t)lane * 64 + q * 8]);
    half8v w1[8];
    if (NOUT == 128) {
#pragma unroll
        for (int q = 0; q < 8; ++q)
            w1[q] = *reinterpret_cast<const half8v*>(&Wt[(size_t)(lane + 64) * 64 + q * 8]);
    }
    float o0 = 0.f, o1 = 0.f;
#pragma unroll
    for (int k = 0; k < 64; ++k) {
        float tk = __shfl(acc[k & 7], k >> 3);
        o0 = fmaf(tk, (float)w0[k >> 3][k & 7], o0);
        if (NOUT == 128) o1 = fmaf(tk, (float)w1[k >> 3][k & 7], o1);
    }
    const float rn = r_nrm[node];
    const float sn = s_nrm[node];
    float y0 = fmaxf(fmaf(o0, rn, bias[lane]), 0.f) * sn;
    if (LAST) {
        float p = y0 * W7[lane];
#pragma unroll
        for (int m = 32; m >= 1; m >>= 1) p += __shfl_xor(p, m);
        if (lane == 0) T7[node] = p;
    } else {
        Y16[(size_t)node * NOUT + lane] = (_Float16)y0;
        if (NOUT == 128) {
            float y1 = fmaxf(fmaf(o1, rn, bias[lane + 64]), 0.f) * sn;
            Y16[(size_t)node * NOUT + 64 + lane] = (_Float16)y1;
        }
    }
}

// ---------------- final scalar aggregation ----------------

__global__ __launch_bounds__(256) void agg1_kernel(const float* __restrict__ T,
                                                   const int* __restrict__ csr,
                                                   const int* __restrict__ row_off,
                                                   const float* __restrict__ r_nrm,
                                                   const float* __restrict__ bias,
                                                   float* __restrict__ Y, int N) {
    const int node = blockIdx.x * 16 + (threadIdx.x >> 4);
    const int l = threadIdx.x & 15;
    if (node >= N) return;
    const int lo = row_off[node];
    const int hi = row_off[node + 1];
    float acc = 0.f;
    for (int e = lo + l; e < hi; e += 16) acc += T[csr[e]];
#pragma unroll
    for (int m = 8; m >= 1; m >>= 1) acc += __shfl_xor(acc, m);
    if (l == 0) Y[node] = fmaf(acc, r_nrm[node], bias[0]);
}

// ---------------- host ----------------

extern "C" void kernel_launch(void* const* d_in, const int* in_sizes, int n_in,
                              void* d_out, int out_size, void* d_ws, size_t ws_size,
                              hipStream_t stream) {
    const float* in_feat = (const float*)d_in[0];
    const int* src = (const int*)d_in[1];
    const int* dst = (const int*)d_in[2];
    const float* W1 = (const float*)d_in[3];  const float* B1 = (const float*)d_in[4];
    const float* W2 = (const float*)d_in[5];  const float* B2 = (const float*)d_in[6];
    const float* W3 = (const float*)d_in[7];  const float* B3 = (const float*)d_in[8];
    const float* W4 = (const float*)d_in[9];  const float* B4 = (const float*)d_in[10];
    const float* W5 = (const float*)d_in[11]; const float* B5 = (const float*)d_in[12];
    const float* W6 = (const float*)d_in[13]; const float* B6 = (const float*)d_in[14];
    const float* W7 = (const float*)d_in[15]; const float* B7 = (const float*)d_in[16];

    const int N = in_sizes[0] / IN_F;        // 40000
    const int E = in_sizes[1];               // 640000
    const int N2 = NSHARD << SHB;            // 40960 (padded)
    float* out = (float*)d_out;

    // workspace layout (256B aligned)
    char* w = (char*)d_ws;
    auto alloc = [&](size_t bytes) { char* p = w; w += (bytes + 255) & ~(size_t)255; return p; };
    int* csr      = (int*)alloc((size_t)E * 4);
    int* row_off  = (int*)alloc((size_t)(N + 1) * 4);
    int* in_deg   = (int*)alloc((size_t)N2 * 4);
    int* blockSums= (int*)alloc(64 * 4);
    int* blockOffs= (int*)alloc(64 * 4);
    float* out_nrm= (float*)alloc((size_t)N2 * 4);
    float* in_nrm = (float*)alloc((size_t)N2 * 4);
    float* t7     = (float*)alloc((size_t)N * 4);
    const int dims[8] = {128, 64, 128, 128, 64, 64, 64, 1};
    unsigned short* wth[6]; unsigned short* wtl[6];
    for (int i = 0; i < 6; ++i) {
        size_t kn = (size_t)dims[i] * dims[i + 1];
        wth[i] = (unsigned short*)alloc(kn * 2);
        wtl[i] = (unsigned short*)alloc(kn * 2);
    }
    // fp16 transposed copies for fused GEMV layers (W2, W5, W6)
    _Float16* w2t16 = (_Float16*)alloc((size_t)64 * 128 * 2);
    _Float16* w5t16 = (_Float16*)alloc((size_t)64 * 64 * 2);
    _Float16* w6t16 = (_Float16*)alloc((size_t)64 * 64 * 2);
    _Float16* h0 = (_Float16*)alloc((size_t)N * 128 * 2);   // 10.24 MB
    _Float16* h1 = (_Float16*)alloc((size_t)N * 128 * 2);
    // hist scratch (2*NSHARD*NSLICE*8192*4 = 19.66 MB) aliases h0+h1 (20.48 MB);
    // consumed by fill2 before L1 writes h0.
    int* scratch = (int*)h0;
    (void)ws_size; (void)n_in; (void)out_size;

    const int TB = 256;
    const int NB = N2 / 1024;   // 40

    // weight split/transpose
    WPack wp;
    const float* Ws[6] = {W1, W2, W3, W4, W5, W6};
    _Float16* t16s[6] = {nullptr, w2t16, nullptr, nullptr, w5t16, w6t16};
    for (int i = 0; i < 6; ++i) wp.d[i] = {Ws[i], wth[i], wtl[i], t16s[i], dims[i], dims[i + 1]};
    split_w_kernel<<<dim3(6, 64), TB, 0, stream>>>(wp);

    // degrees + norms + CSR (atomic-free)
    hist2_kernel<<<dim3(NSLICE, NSHARD, 2), TB, 0, stream>>>(src, dst, scratch, E);
    hist_reduce_blk<<<NB, TB, 0, stream>>>(scratch, in_deg, out_nrm, in_nrm, blockSums);
    scan_top_kernel<<<1, 64, 0, stream>>>(blockSums, blockOffs, row_off, NB, N);
    scan_fill_kernel<<<NB, TB, 0, stream>>>(in_deg, blockOffs, row_off, N);
    slice_base_kernel<<<(N + TB - 1) / TB, TB, 0, stream>>>(scratch, row_off, N);
    fill2_kernel<<<dim3(NSLICE, NSHARD), TB, 0, stream>>>(src, dst, scratch, csr, E);

    const int gridN4 = (N + 3) / 4;   // one node per wave
    const int MB = (N + 63) / 64;     // 625

    // L1: 128->64 mult-first. h0 = t1 = (x*s)@W1 ; h1 = g1 = relu(agg(t1)*r+B1)*s
    gemm_mfma_f32<128, 64><<<MB, TB, 0, stream>>>(in_feat, wth[0], wtl[0], out_nrm, h0, N);
    agg_h16<64, true><<<gridN4, TB, 0, stream>>>(h0, csr, row_off, in_nrm, out_nrm, B1, h1, N);

    // L2: 64->128 fused agg+GEMV. h0 = g2 = relu(agg(g1)@W2*r+B2)*s
    fused_agv<128, false><<<gridN4, TB, 0, stream>>>(
        h1, csr, row_off, w2t16, in_nrm, out_nrm, B2, nullptr, h0, nullptr, N);

    // L3: 128->128 agg-first. h1 = t3 = agg(g2) ; h0 = g3 = relu(t3@W3*r+B3)*s
    agg_h16<128, false><<<gridN4, TB, 0, stream>>>(h0, csr, row_off, nullptr, nullptr, nullptr, h1, N);
    gemm_h16<128, 128, true><<<MB, TB, 0, stream>>>(h1, wth[2], wtl[2], in_nrm, out_nrm, B3, h0, N);

    // L4: 128->64 mult-first. h1 = t4 = g3@W4 ; h0 = g4 = relu(agg(t4)*r+B4)*s
    gemm_h16<128, 64, false><<<MB, TB, 0, stream>>>(h0, wth[3], wtl[3], nullptr, nullptr, nullptr, h1, N);
    agg_h16<64, true><<<gridN4, TB, 0, stream>>>(h1, csr, row_off, in_nrm, out_nrm, B4, h0, N);

    // L5: 64->64 fused agg+GEMV. h1 = g5
    fused_agv<64, false><<<gridN4, TB, 0, stream>>>(
        h0, csr, row_off, w5t16, in_nrm, out_nrm, B5, nullptr, h1, nullptr, N);

    // L6+L7 GEMV: fused agg+GEMV+W7 dot. t7 = (relu(agg(g5)@W6*r+B6)*s)@W7
    fused_agv<64, true><<<gridN4, TB, 0, stream>>>(
        h1, csr, row_off, w6t16, in_nrm, out_nrm, B6, W7, nullptr, t7, N);

    // out = agg(t7)*r + B7
    agg1_kernel<<<(N + 15) / 16, TB, 0, stream>>>(t7, csr, row_off, in_nrm, B7, out, N);
}

// Round 9
// 294.454 us; speedup vs baseline: 1.2863x; 1.2863x over previous
//
#include <hip/hip_runtime.h>
#include <hip/hip_bf16.h>

// GCN 7-layer forward on MI355X. R9:
//  - REVERT R8 fused_agv (shfl-GEMV was LDS-pipe/dep-chain bound: 87us @21%
//    VALUBusy; MFMA GEMM from memory wins). Back to R7 layer structure.
//  - dispatch-count attack (22 -> 18): split_w merged into hist2 (z-plane),
//    scan_top merged into scan_fill (redundant per-block top-scan),
//    hist_reduce absorbs scan_blk (R8), L7 GEMV folded into L6 epilogue.

#define IN_F 128
#define NSLICE 60
#define SHB 13          // 8192 nodes/shard, 32 KB LDS
#define NSHARD 5        // ceil(40000/8192)

typedef __attribute__((ext_vector_type(8))) short short8v;   // 8 bf16
typedef __attribute__((ext_vector_type(4))) float f32x4;
typedef __attribute__((ext_vector_type(8))) _Float16 half8v; // 16 B

static __device__ __forceinline__ unsigned short f2bf(float x) {
    unsigned u = __builtin_bit_cast(unsigned, x);
    unsigned r = (u + 0x7FFFu + ((u >> 16) & 1u)) >> 16;   // rn-even
    return (unsigned short)r;
}
static __device__ __forceinline__ float bf2f(unsigned short h) {
    unsigned u = ((unsigned)h) << 16;
    return __builtin_bit_cast(float, u);
}

// ---------------- weight descriptors ----------------

struct WDesc { const float* w; unsigned short* th; unsigned short* tl; int K; int N; int cum; };
struct WPack { WDesc d[6]; int total; };

// ---------------- prep: LDS histogram (z=0,1) + weight split (z=2) ----------------
// grid (NSLICE, NSHARD, 3)

__global__ __launch_bounds__(256) void prep_kernel(const int* __restrict__ src,
                                                   const int* __restrict__ dst,
                                                   int* __restrict__ scratch,
                                                   WPack p, int E) {
    constexpr int SH = 1 << SHB;
    __shared__ int h[SH];
    const int t = threadIdx.x;
    const int b = blockIdx.x;            // edge slice
    const int s = blockIdx.y;            // node shard
    const int z = blockIdx.z;            // 0=src hist, 1=dst hist, 2=split_w
    if (z == 2) {
        int i = (b + NSLICE * s) * 256 + t;
        if (i >= p.total) return;
        int wi = 0;
#pragma unroll
        for (int q = 1; q < 6; ++q) if (i >= p.d[q].cum) wi = q;
        WDesc d = p.d[wi];
        int local = i - d.cum;
        int k = local / d.N, n = local - k * d.N;
        float v = d.w[local];
        unsigned short hh = f2bf(v);
        d.th[(size_t)n * d.K + k] = hh;
        d.tl[(size_t)n * d.K + k] = f2bf(v - bf2f(hh));
        return;
    }
    const int* idx = z ? dst : src;
    for (int i = t; i < SH; i += 256) h[i] = 0;
    __syncthreads();
    const int per = (E + NSLICE - 1) / NSLICE;
    const int lo = b * per;
    const int hiE = min(lo + per, E);
    const int base = s << SHB;
    for (int e = lo + t; e < hiE; e += 256) {
        unsigned a = (unsigned)(idx[e] - base);
        if (a < (unsigned)SH) atomicAdd(&h[a], 1);
    }
    __syncthreads();
    int* so = scratch + ((size_t)((z * NSHARD + s) * NSLICE + b) << SHB);
    for (int i = t; i < SH; i += 256) so[i] = h[i];
}

// ---------------- degree sums + norms + per-1024-node block sums ----------------
// grid = 40 blocks (40960 padded nodes), 4 nodes/thread

__global__ __launch_bounds__(256) void hist_reduce_blk(
    const int* __restrict__ scratch, int* __restrict__ in_deg,
    float* __restrict__ out_nrm, float* __restrict__ in_nrm,
    int* __restrict__ blockSums) {
    constexpr int SH = 1 << SHB;
    __shared__ int ws4[4];
    const int t = threadIdx.x;
    const int base = blockIdx.x * 1024 + t * 4;
    const int s = base >> SHB;
    const int i = base & (SH - 1);
    int od[4] = {0, 0, 0, 0}, id[4] = {0, 0, 0, 0};
    const int* po = scratch + (((size_t)s * NSLICE) << SHB) + i;
    const int* pi = scratch + (((size_t)(NSHARD + s) * NSLICE) << SHB) + i;
    for (int b = 0; b < NSLICE; ++b) {
        int4 o4 = *reinterpret_cast<const int4*>(po + ((size_t)b << SHB));
        int4 i4 = *reinterpret_cast<const int4*>(pi + ((size_t)b << SHB));
        od[0] += o4.x; od[1] += o4.y; od[2] += o4.z; od[3] += o4.w;
        id[0] += i4.x; id[1] += i4.y; id[2] += i4.z; id[3] += i4.w;
    }
    *reinterpret_cast<int4*>(&in_deg[base]) = make_int4(id[0], id[1], id[2], id[3]);
    float4 onf, inf;
    onf.x = od[0] > 0 ? rsqrtf((float)od[0]) : 0.f;
    onf.y = od[1] > 0 ? rsqrtf((float)od[1]) : 0.f;
    onf.z = od[2] > 0 ? rsqrtf((float)od[2]) : 0.f;
    onf.w = od[3] > 0 ? rsqrtf((float)od[3]) : 0.f;
    inf.x = id[0] > 0 ? rsqrtf((float)id[0]) : 0.f;
    inf.y = id[1] > 0 ? rsqrtf((float)id[1]) : 0.f;
    inf.z = id[2] > 0 ? rsqrtf((float)id[2]) : 0.f;
    inf.w = id[3] > 0 ? rsqrtf((float)id[3]) : 0.f;
    *reinterpret_cast<float4*>(&out_nrm[base]) = onf;
    *reinterpret_cast<float4*>(&in_nrm[base]) = inf;
    int ssum = id[0] + id[1] + id[2] + id[3];
#pragma unroll
    for (int off = 32; off > 0; off >>= 1) ssum += __shfl_down(ssum, off);
    if ((t & 63) == 0) ws4[t >> 6] = ssum;
    __syncthreads();
    if (t == 0) blockSums[blockIdx.x] = ws4[0] + ws4[1] + ws4[2] + ws4[3];
}

// ---------------- scan_fill with built-in top scan ----------------
// 40 blocks; wave 0 reduces blockSums[b < blockIdx.x] for the block offset.

__global__ __launch_bounds__(256) void scan_fill2(const int* __restrict__ deg,
                                                  const int* __restrict__ blockSums,
                                                  int* __restrict__ row_off,
                                                  int NBtop, int N, int E) {
    __shared__ int sOff;
    __shared__ int wtot[4];
    const int t = threadIdx.x;
    const int lane = t & 63;
    const int wid = t >> 6;
    // wave 0: exclusive prefix for this block
    if (wid == 0) {
        int v = (lane < NBtop && lane < blockIdx.x) ? blockSums[lane] : 0;
#pragma unroll
        for (int off = 32; off > 0; off >>= 1) v += __shfl_down(v, off);
        if (lane == 0) sOff = v;
    }
    const int base = blockIdx.x * 1024 + t * 4;
    int4 v = make_int4(0, 0, 0, 0);
    if (base + 3 < N) v = *reinterpret_cast<const int4*>(&deg[base]);
    else if (base < N) {
        v.x = deg[base];
        if (base + 1 < N) v.y = deg[base + 1];
        if (base + 2 < N) v.z = deg[base + 2];
    }
    const int s = v.x + v.y + v.z + v.w;
    int incl = s;
#pragma unroll
    for (int off = 1; off < 64; off <<= 1) {
        int u = __shfl_up(incl, off);
        if (lane >= off) incl += u;
    }
    if (lane == 63) wtot[wid] = incl;
    __syncthreads();
    int pre = sOff + incl - s;
    for (int i = 0; i < wid; ++i) pre += wtot[i];
    if (base < N) {
        int run = pre;
        row_off[base] = run; run += v.x;
        if (base + 1 < N) { row_off[base + 1] = run; run += v.y; }
        if (base + 2 < N) { row_off[base + 2] = run; run += v.z; }
        if (base + 3 < N) { row_off[base + 3] = run; }
    }
    if (blockIdx.x == 0 && t == 0) row_off[N] = E;
}

// per-(slice,node) dst counts -> global base positions
__global__ void slice_base_kernel(int* __restrict__ scratch,
                                  const int* __restrict__ row_off, int N) {
    constexpr int SH = 1 << SHB;
    int n = blockIdx.x * blockDim.x + threadIdx.x;
    if (n >= N) return;
    int s = n >> SHB;
    int i = n & (SH - 1);
    int run = row_off[n];
    for (int b = 0; b < NSLICE; ++b) {
        size_t off = ((size_t)((NSHARD + s) * NSLICE + b) << SHB) + i;
        int c = scratch[off];
        scratch[off] = run;
        run += c;
    }
}

// place edges using LDS cursors seeded from slice bases; no global atomics
__global__ __launch_bounds__(256) void fill2_kernel(const int* __restrict__ src,
                                                    const int* __restrict__ dst,
                                                    const int* __restrict__ scratch,
                                                    int* __restrict__ csr, int E) {
    constexpr int SH = 1 << SHB;
    __shared__ int cur[SH];
    const int t = threadIdx.x;
    const int b = blockIdx.x;   // slice
    const int s = blockIdx.y;   // shard
    const int* base = scratch + ((size_t)((NSHARD + s) * NSLICE + b) << SHB);
    for (int i = t; i < SH; i += 256) cur[i] = base[i];
    __syncthreads();
    const int per = (E + NSLICE - 1) / NSLICE;
    const int lo = b * per;
    const int hiE = min(lo + per, E);
    const int nb = s << SHB;
    for (int e = lo + t; e < hiE; e += 256) {
        unsigned a = (unsigned)(dst[e] - nb);
        if (a < (unsigned)SH) {
            int pos = atomicAdd(&cur[a], 1);
            csr[pos] = src[e];
        }
    }
}

// ---------------- L1 GEMM: fp32 input, scale+split in registers ----------------

template<int K, int NOUT>
__global__ __launch_bounds__(256) void gemm_mfma_f32(
    const float* __restrict__ X,
    const unsigned short* __restrict__ Bh, const unsigned short* __restrict__ Bl,
    const float* __restrict__ pre, _Float16* __restrict__ Y16, int M) {
    constexpr int NT = NOUT / 16;
    const int lane = threadIdx.x & 63;
    const int wv = threadIdx.x >> 6;
    const int r0 = blockIdx.x * 64 + wv * 16;
    const int arow = r0 + (lane & 15);
    const int kg = (lane >> 4) * 8;
    const float sc = pre[arow];

    f32x4 acc[NT];
#pragma unroll
    for (int n = 0; n < NT; ++n) acc[n] = (f32x4){0.f, 0.f, 0.f, 0.f};

    for (int kk = 0; kk < K; kk += 32) {
        const float* ap = &X[(size_t)arow * K + kk + kg];
        float4 v0 = *reinterpret_cast<const float4*>(ap);
        float4 v1 = *reinterpret_cast<const float4*>(ap + 4);
        float a[8] = {v0.x, v0.y, v0.z, v0.w, v1.x, v1.y, v1.z, v1.w};
        short8v a_h, a_l;
#pragma unroll
        for (int j = 0; j < 8; ++j) {
            float f = a[j] * sc;
            unsigned short hh = f2bf(f);
            a_h[j] = (short)hh;
            a_l[j] = (short)f2bf(f - bf2f(hh));
        }
#pragma unroll
        for (int n = 0; n < NT; ++n) {
            int col = n * 16 + (lane & 15);
            short8v b_h = *reinterpret_cast<const short8v*>(Bh + (size_t)col * K + kk + kg);
            short8v b_l = *reinterpret_cast<const short8v*>(Bl + (size_t)col * K + kk + kg);
            acc[n] = __builtin_amdgcn_mfma_f32_16x16x32_bf16(a_h, b_h, acc[n], 0, 0, 0);
            acc[n] = __builtin_amdgcn_mfma_f32_16x16x32_bf16(a_h, b_l, acc[n], 0, 0, 0);
            acc[n] = __builtin_amdgcn_mfma_f32_16x16x32_bf16(a_l, b_h, acc[n], 0, 0, 0);
        }
    }
    const int c0 = lane & 15;
    const int rr = r0 + (lane >> 4) * 4;
#pragma unroll
    for (int n = 0; n < NT; ++n) {
        const int col = n * 16 + c0;
#pragma unroll
        for (int j = 0; j < 4; ++j)
            Y16[(size_t)(rr + j) * NOUT + col] = (_Float16)acc[n][j];
    }
}

// ---------------- GEMM: fp16 A, split to bf16 hi/lo in registers ----------------
// EPI: relu(acc*r + bias)*s epilogue. GEMV7: also dot rows with W7 -> T7
// (output tensor itself not written; used for L6+L7 fold).

template<int K, int NOUT, bool EPI, bool GEMV7>
__global__ __launch_bounds__(256) void gemm_h16(
    const _Float16* __restrict__ X,
    const unsigned short* __restrict__ Bh, const unsigned short* __restrict__ Bl,
    const float* __restrict__ r_nrm, const float* __restrict__ s_nrm,
    const float* __restrict__ bias, const float* __restrict__ W7,
    _Float16* __restrict__ Y16, float* __restrict__ T7, int M) {
    constexpr int NT = NOUT / 16;
    const int lane = threadIdx.x & 63;
    const int wv = threadIdx.x >> 6;
    const int r0 = blockIdx.x * 64 + wv * 16;
    const int arow = r0 + (lane & 15);
    const int kg = (lane >> 4) * 8;

    f32x4 acc[NT];
#pragma unroll
    for (int n = 0; n < NT; ++n) acc[n] = (f32x4){0.f, 0.f, 0.f, 0.f};

    for (int kk = 0; kk < K; kk += 32) {
        half8v av = *reinterpret_cast<const half8v*>(&X[(size_t)arow * K + kk + kg]);
        short8v a_h, a_l;
#pragma unroll
        for (int j = 0; j < 8; ++j) {
            float f = (float)av[j];
            unsigned short hh = f2bf(f);
            a_h[j] = (short)hh;
            a_l[j] = (short)f2bf(f - bf2f(hh));
        }
#pragma unroll
        for (int n = 0; n < NT; ++n) {
            int col = n * 16 + (lane & 15);
            short8v b_h = *reinterpret_cast<const short8v*>(Bh + (size_t)col * K + kk + kg);
            short8v b_l = *reinterpret_cast<const short8v*>(Bl + (size_t)col * K + kk + kg);
            acc[n] = __builtin_amdgcn_mfma_f32_16x16x32_bf16(a_h, b_h, acc[n], 0, 0, 0);
            acc[n] = __builtin_amdgcn_mfma_f32_16x16x32_bf16(a_h, b_l, acc[n], 0, 0, 0);
            acc[n] = __builtin_amdgcn_mfma_f32_16x16x32_bf16(a_l, b_h, acc[n], 0, 0, 0);
        }
    }
    const int c0 = lane & 15;
    const int rr = r0 + (lane >> 4) * 4;
    if (GEMV7) {
        // epilogue + per-row dot with W7, reduce over the 16 col lanes
        float w7c[NT];
#pragma unroll
        for (int n = 0; n < NT; ++n) w7c[n] = W7[n * 16 + c0];
#pragma unroll
        for (int j = 0; j < 4; ++j) {
            const int row = rr + j;
            const float rn = r_nrm[row];
            const float sn = s_nrm[row];
            float p = 0.f;
#pragma unroll
            for (int n = 0; n < NT; ++n) {
                float y = fmaf(acc[n][j], rn, bias[n * 16 + c0]);
                y = fmaxf(y, 0.f) * sn;
                p = fmaf(y, w7c[n], p);
            }
#pragma unroll
            for (int m = 8; m >= 1; m >>= 1) p += __shfl_xor(p, m);
            if (c0 == 0) T7[row] = p;
        }
    } else {
#pragma unroll
        for (int n = 0; n < NT; ++n) {
            const int col = n * 16 + c0;
            const float bcol = EPI ? bias[col] : 0.f;
#pragma unroll
            for (int j = 0; j < 4; ++j) {
                const int row = rr + j;
                float y = acc[n][j];
                if (EPI) {
                    y = fmaf(y, r_nrm[row], bcol);
                    y = fmaxf(y, 0.f);
                    y *= s_nrm[row];
                }
                Y16[(size_t)row * NOUT + col] = (_Float16)y;
            }
        }
    }
}

// ---------------- fp16 CSR aggregation, 2x unrolled, fp16 out ----------------

template<int F, bool EPI>
__global__ __launch_bounds__(256) void agg_h16(
    const _Float16* __restrict__ X, const int* __restrict__ csr,
    const int* __restrict__ row_off, const float* __restrict__ r_nrm,
    const float* __restrict__ s_nrm, const float* __restrict__ bias,
    _Float16* __restrict__ Y16, int N) {
    constexpr int LPE = F / 8;
    constexpr int EPW = 64 / LPE;
    const int lane = threadIdx.x & 63;
    const int node = blockIdx.x * (blockDim.x >> 6) + (threadIdx.x >> 6);
    if (node >= N) return;
    const int g = lane / LPE;
    const int c = lane % LPE;
    const int lo = row_off[node];
    const int hi = row_off[node + 1];
    float acc[8], acc2[8];
#pragma unroll
    for (int j = 0; j < 8; ++j) { acc[j] = 0.f; acc2[j] = 0.f; }
    int e = lo + g;
    for (; e + EPW < hi; e += 2 * EPW) {
        int s0 = csr[e];
        int s1 = csr[e + EPW];
        half8v x0 = *reinterpret_cast<const half8v*>(&X[(size_t)s0 * F + c * 8]);
        half8v x1 = *reinterpret_cast<const half8v*>(&X[(size_t)s1 * F + c * 8]);
#pragma unroll
        for (int j = 0; j < 8; ++j) { acc[j] += (float)x0[j]; acc2[j] += (float)x1[j]; }
    }
    if (e < hi) {
        int s0 = csr[e];
        half8v x0 = *reinterpret_cast<const half8v*>(&X[(size_t)s0 * F + c * 8]);
#pragma unroll
        for (int j = 0; j < 8; ++j) acc[j] += (float)x0[j];
    }
#pragma unroll
    for (int j = 0; j < 8; ++j) acc[j] += acc2[j];
#pragma unroll
    for (int m = LPE; m < 64; m <<= 1) {
#pragma unroll
        for (int j = 0; j < 8; ++j) acc[j] += __shfl_xor(acc[j], m);
    }
    if (lane < LPE) {
        half8v o;
        if (EPI) {
            float rn = r_nrm[node];
            float sn = s_nrm[node];
#pragma unroll
            for (int j = 0; j < 8; ++j) {
                float y = fmaf(acc[j], rn, bias[lane * 8 + j]);
                o[j] = (_Float16)(fmaxf(y, 0.f) * sn);
            }
        } else {
#pragma unroll
            for (int j = 0; j < 8; ++j) o[j] = (_Float16)acc[j];
        }
        *reinterpret_cast<half8v*>(&Y16[(size_t)node * F + lane * 8]) = o;
    }
}

// ---------------- final scalar aggregation ----------------

__global__ __launch_bounds__(256) void agg1_kernel(const float* __restrict__ T,
                                                   const int* __restrict__ csr,
                                                   const int* __restrict__ row_off,
                                                   const float* __restrict__ r_nrm,
                                                   const float* __restrict__ bias,
                                                   float* __restrict__ Y, int N) {
    const int node = blockIdx.x * 16 + (threadIdx.x >> 4);
    const int l = threadIdx.x & 15;
    if (node >= N) return;
    const int lo = row_off[node];
    const int hi = row_off[node + 1];
    float acc = 0.f;
    for (int e = lo + l; e < hi; e += 16) acc += T[csr[e]];
#pragma unroll
    for (int m = 8; m >= 1; m >>= 1) acc += __shfl_xor(acc, m);
    if (l == 0) Y[node] = fmaf(acc, r_nrm[node], bias[0]);
}

// ---------------- host ----------------

extern "C" void kernel_launch(void* const* d_in, const int* in_sizes, int n_in,
                              void* d_out, int out_size, void* d_ws, size_t ws_size,
                              hipStream_t stream) {
    const float* in_feat = (const float*)d_in[0];
    const int* src = (const int*)d_in[1];
    const int* dst = (const int*)d_in[2];
    const float* W1 = (const float*)d_in[3];  const float* B1 = (const float*)d_in[4];
    const float* W2 = (const float*)d_in[5];  const float* B2 = (const float*)d_in[6];
    const float* W3 = (const float*)d_in[7];  const float* B3 = (const float*)d_in[8];
    const float* W4 = (const float*)d_in[9];  const float* B4 = (const float*)d_in[10];
    const float* W5 = (const float*)d_in[11]; const float* B5 = (const float*)d_in[12];
    const float* W6 = (const float*)d_in[13]; const float* B6 = (const float*)d_in[14];
    const float* W7 = (const float*)d_in[15]; const float* B7 = (const float*)d_in[16];

    const int N = in_sizes[0] / IN_F;        // 40000
    const int E = in_sizes[1];               // 640000
    const int N2 = NSHARD << SHB;            // 40960 (padded)
    float* out = (float*)d_out;

    // workspace layout (256B aligned)
    char* w = (char*)d_ws;
    auto alloc = [&](size_t bytes) { char* p = w; w += (bytes + 255) & ~(size_t)255; return p; };
    int* csr      = (int*)alloc((size_t)E * 4);
    int* row_off  = (int*)alloc((size_t)(N + 1) * 4);
    int* in_deg   = (int*)alloc((size_t)N2 * 4);
    int* blockSums= (int*)alloc(64 * 4);
    float* out_nrm= (float*)alloc((size_t)N2 * 4);
    float* in_nrm = (float*)alloc((size_t)N2 * 4);
    float* t7     = (float*)alloc((size_t)N * 4);
    const int dims[8] = {128, 64, 128, 128, 64, 64, 64, 1};
    unsigned short* wth[6]; unsigned short* wtl[6];
    for (int i = 0; i < 6; ++i) {
        size_t kn = (size_t)dims[i] * dims[i + 1];
        wth[i] = (unsigned short*)alloc(kn * 2);
        wtl[i] = (unsigned short*)alloc(kn * 2);
    }
    _Float16* h0 = (_Float16*)alloc((size_t)N * 128 * 2);   // 10.24 MB
    _Float16* h1 = (_Float16*)alloc((size_t)N * 128 * 2);
    // hist scratch (2*NSHARD*NSLICE*8192*4 = 19.66 MB) aliases h0+h1 (20.48 MB);
    // consumed by fill2 before L1 writes h0.
    int* scratch = (int*)h0;
    (void)ws_size; (void)n_in; (void)out_size;

    const int TB = 256;
    const int NB = N2 / 1024;   // 40

    // weight pack with cumulative offsets
    WPack wp;
    const float* Ws[6] = {W1, W2, W3, W4, W5, W6};
    int cum = 0;
    for (int i = 0; i < 6; ++i) {
        wp.d[i] = {Ws[i], wth[i], wtl[i], dims[i], dims[i + 1], cum};
        cum += dims[i] * dims[i + 1];
    }
    wp.total = cum;   // 49152

    // CSR + norms (atomic-free), weights split in the same first dispatch
    prep_kernel<<<dim3(NSLICE, NSHARD, 3), TB, 0, stream>>>(src, dst, scratch, wp, E);
    hist_reduce_blk<<<NB, TB, 0, stream>>>(scratch, in_deg, out_nrm, in_nrm, blockSums);
    scan_fill2<<<NB, TB, 0, stream>>>(in_deg, blockSums, row_off, NB, N, E);
    slice_base_kernel<<<(N + TB - 1) / TB, TB, 0, stream>>>(scratch, row_off, N);
    fill2_kernel<<<dim3(NSLICE, NSHARD), TB, 0, stream>>>(src, dst, scratch, csr, E);

    const int gridN4 = (N + 3) / 4;   // one node per wave
    const int MB = (N + 63) / 64;     // 625

    // L1: 128->64 mult-first. h0 = t1 = (x*s)@W1 ; h1 = g1 = relu(agg(t1)*r+B1)*s
    gemm_mfma_f32<128, 64><<<MB, TB, 0, stream>>>(in_feat, wth[0], wtl[0], out_nrm, h0, N);
    agg_h16<64, true><<<gridN4, TB, 0, stream>>>(h0, csr, row_off, in_nrm, out_nrm, B1, h1, N);

    // L2: 64->128 agg-first. h0 = t2 = agg(g1) ; h1 = g2 = relu(t2@W2*r+B2)*s
    agg_h16<64, false><<<gridN4, TB, 0, stream>>>(h1, csr, row_off, nullptr, nullptr, nullptr, h0, N);
    gemm_h16<64, 128, true, false><<<MB, TB, 0, stream>>>(
        h0, wth[1], wtl[1], in_nrm, out_nrm, B2, nullptr, h1, nullptr, N);

    // L3: 128->128 agg-first. h0 = t3 = agg(g2) ; h1 = g3
    agg_h16<128, false><<<gridN4, TB, 0, stream>>>(h1, csr, row_off, nullptr, nullptr, nullptr, h0, N);
    gemm_h16<128, 128, true, false><<<MB, TB, 0, stream>>>(
        h0, wth[2], wtl[2], in_nrm, out_nrm, B3, nullptr, h1, nullptr, N);

    // L4: 128->64 mult-first. h0 = t4 = g3@W4 ; h1 = g4 = relu(agg(t4)*r+B4)*s
    gemm_h16<128, 64, false, false><<<MB, TB, 0, stream>>>(
        h1, wth[3], wtl[3], nullptr, nullptr, nullptr, nullptr, h0, nullptr, N);
    agg_h16<64, true><<<gridN4, TB, 0, stream>>>(h0, csr, row_off, in_nrm, out_nrm, B4, h1, N);

    // L5: 64->64 agg-first. h0 = t5 = agg(g4) ; h1 = g5
    agg_h16<64, false><<<gridN4, TB, 0, stream>>>(h1, csr, row_off, nullptr, nullptr, nullptr, h0, N);
    gemm_h16<64, 64, true, false><<<MB, TB, 0, stream>>>(
        h0, wth[4], wtl[4], in_nrm, out_nrm, B5, nullptr, h1, nullptr, N);

    // L6: 64->64 agg-first. h0 = t6 = agg(g5) ; gemm+epilogue+W7-dot -> t7
    agg_h16<64, false><<<gridN4, TB, 0, stream>>>(h1, csr, row_off, nullptr, nullptr, nullptr, h0, N);
    gemm_h16<64, 64, true, true><<<MB, TB, 0, stream>>>(
        h0, wth[5], wtl[5], in_nrm, out_nrm, B6, W7, nullptr, t7, N);

    // out = agg(t7)*r + B7
    agg1_kernel<<<(N + 15) / 16, TB, 0, stream>>>(t7, csr, row_off, in_nrm, B7, out, N);
}